// Round 1
// baseline (4052.847 us; speedup 1.0000x reference)
//
#include <hip/hip_runtime.h>

namespace {
constexpr int kB = 8;
constexpr int kC = 512;
constexpr int kCK = 64;
constexpr int kN = 4096;
}

// Out[b][n][k] = sum_c x[b][c][n] * W[k][c] + bias[k]
// grid: (N/64, Kout/64, B), block 256
__global__ __launch_bounds__(256)
void proj_kernel(const float* __restrict__ x, const float* __restrict__ W,
                 const float* __restrict__ bias, float* __restrict__ out,
                 int Kout)
{
  const int t = threadIdx.x;
  const int nt = blockIdx.x;
  const int kt = blockIdx.y;
  const int b  = blockIdx.z;

  const float* xb = x + (size_t)b * kC * kN + nt * 64;
  float* ob = out + ((size_t)b * kN + (size_t)nt * 64) * Kout + kt * 64;

  __shared__ float xs[16][64];   // [c][n]
  __shared__ float wst[16][65];  // [c][k] transposed, padded

  const int tn = t & 15;
  const int tk = t >> 4;

  float acc[4][4];
#pragma unroll
  for (int i = 0; i < 4; ++i)
#pragma unroll
    for (int j = 0; j < 4; ++j) acc[i][j] = 0.f;

  for (int c0 = 0; c0 < kC; c0 += 16) {
#pragma unroll
    for (int r = 0; r < 4; ++r) {
      const int f = t + 256 * r;
      xs[f >> 6][f & 63] = xb[(size_t)(c0 + (f >> 6)) * kN + (f & 63)];
    }
#pragma unroll
    for (int r = 0; r < 4; ++r) {
      const int f = t + 256 * r;
      wst[f & 15][f >> 4] = W[(size_t)(kt * 64 + (f >> 4)) * kC + (c0 + (f & 15))];
    }
    __syncthreads();
#pragma unroll
    for (int cc = 0; cc < 16; ++cc) {
      float xv[4], wv[4];
#pragma unroll
      for (int i = 0; i < 4; ++i) xv[i] = xs[cc][tn * 4 + i];
#pragma unroll
      for (int j = 0; j < 4; ++j) wv[j] = wst[cc][tk * 4 + j];
#pragma unroll
      for (int i = 0; i < 4; ++i)
#pragma unroll
        for (int j = 0; j < 4; ++j) acc[i][j] += xv[i] * wv[j];
    }
    __syncthreads();
  }

#pragma unroll
  for (int j = 0; j < 4; ++j) {
    const float bv = bias[kt * 64 + tk * 4 + j];
#pragma unroll
    for (int i = 0; i < 4; ++i) {
      ob[(size_t)(tn * 4 + i) * Kout + tk * 4 + j] = acc[i][j] + bv;
    }
  }
}

// Per-row max and sum-of-exp of scores = F (.) G^T.
// grid: (N/64, B), block 256
__global__ __launch_bounds__(256)
void stats_kernel(const float* __restrict__ F, const float* __restrict__ G,
                  float* __restrict__ rowmax, float* __restrict__ rowsum)
{
  const int t = threadIdx.x;
  const int qt = blockIdx.x;
  const int b  = blockIdx.y;

  const float* Fb = F + (size_t)b * kN * kCK;
  const float* Gb = G + (size_t)b * kN * kCK;

  __shared__ float fs[64][68];
  __shared__ float gs[64][68];

  const int tm = t & 15;
  const int tq = t >> 4;

#pragma unroll
  for (int r = 0; r < 16; ++r) {
    const int f = t + 256 * r;
    fs[f >> 6][f & 63] = Fb[(size_t)qt * 64 * kCK + f];
  }

  float rmax[4], rsum[4];
#pragma unroll
  for (int i = 0; i < 4; ++i) { rmax[i] = -3.0e38f; rsum[i] = 0.f; }

  for (int mt = 0; mt < kN / 64; ++mt) {
#pragma unroll
    for (int r = 0; r < 16; ++r) {
      const int f = t + 256 * r;
      gs[f >> 6][f & 63] = Gb[(size_t)mt * 64 * kCK + f];
    }
    __syncthreads();

    float s[4][4];
#pragma unroll
    for (int i = 0; i < 4; ++i)
#pragma unroll
      for (int j = 0; j < 4; ++j) s[i][j] = 0.f;

#pragma unroll
    for (int k4 = 0; k4 < 64; k4 += 4) {
      float4 fv[4], gv[4];
#pragma unroll
      for (int i = 0; i < 4; ++i) fv[i] = *(const float4*)&fs[tq * 4 + i][k4];
#pragma unroll
      for (int j = 0; j < 4; ++j) gv[j] = *(const float4*)&gs[tm * 4 + j][k4];
#pragma unroll
      for (int i = 0; i < 4; ++i)
#pragma unroll
        for (int j = 0; j < 4; ++j) {
          s[i][j] += fv[i].x * gv[j].x + fv[i].y * gv[j].y +
                     fv[i].z * gv[j].z + fv[i].w * gv[j].w;
        }
    }

#pragma unroll
    for (int i = 0; i < 4; ++i) {
      const float tmax = fmaxf(fmaxf(s[i][0], s[i][1]), fmaxf(s[i][2], s[i][3]));
      const float nm = fmaxf(rmax[i], tmax);
      const float scale = __expf(rmax[i] - nm);
      const float add = __expf(s[i][0] - nm) + __expf(s[i][1] - nm) +
                        __expf(s[i][2] - nm) + __expf(s[i][3] - nm);
      rsum[i] = rsum[i] * scale + add;
      rmax[i] = nm;
    }
    __syncthreads();
  }

  // reduce partials across the 16 tm-groups
  float* red = &gs[0][0];
#pragma unroll
  for (int i = 0; i < 4; ++i) {
    red[(tq * 4 + i) * 16 + tm] = rmax[i];
    red[1024 + (tq * 4 + i) * 16 + tm] = rsum[i];
  }
  __syncthreads();
  if (t < 64) {
    float M = -3.0e38f;
#pragma unroll
    for (int j = 0; j < 16; ++j) M = fmaxf(M, red[t * 16 + j]);
    float S = 0.f;
#pragma unroll
    for (int j = 0; j < 16; ++j) S += red[1024 + t * 16 + j] * __expf(red[t * 16 + j] - M);
    rowmax[(size_t)b * kN + qt * 64 + t] = M;
    rowsum[(size_t)b * kN + qt * 64 + t] = S;
  }
}

// out[b][c][n] = gamma * sum_m softmax(F.G^T)[n][m] * H[m][c] + x[b][c][n]
// grid: (N/64, C/128, B), block 256
__global__ __launch_bounds__(256)
void pv_kernel(const float* __restrict__ x, const float* __restrict__ F,
               const float* __restrict__ G, const float* __restrict__ Hh,
               const float* __restrict__ rowmax, const float* __restrict__ rowsum,
               const float* __restrict__ gamma, float* __restrict__ out)
{
  const int t = threadIdx.x;
  const int qt = blockIdx.x;
  const int cs = blockIdx.y;
  const int b  = blockIdx.z;

  const float* Fb = F + (size_t)b * kN * kCK;
  const float* Gb = G + (size_t)b * kN * kCK;
  const float* Hb = Hh + (size_t)b * kN * kC;

  __shared__ float fs[64][68];   // F tile [q][k]
  __shared__ float gps[64][68];  // G tile [m][k], then P tile [q][m]
  __shared__ float hs[64][132];  // H tile [m][c], then O tile [q][c]

  const int tc = t & 15;
  const int tq = t >> 4;

#pragma unroll
  for (int r = 0; r < 16; ++r) {
    const int f = t + 256 * r;
    fs[f >> 6][f & 63] = Fb[(size_t)qt * 64 * kCK + f];
  }

  float rmax[4], rsinv[4];
#pragma unroll
  for (int i = 0; i < 4; ++i) {
    const size_t q = (size_t)b * kN + qt * 64 + tq * 4 + i;
    rmax[i] = rowmax[q];
    rsinv[i] = 1.f / rowsum[q];
  }

  float acc[4][8];
#pragma unroll
  for (int i = 0; i < 4; ++i)
#pragma unroll
    for (int u = 0; u < 8; ++u) acc[i][u] = 0.f;

  for (int mt = 0; mt < kN / 64; ++mt) {
#pragma unroll
    for (int r = 0; r < 16; ++r) {
      const int f = t + 256 * r;
      gps[f >> 6][f & 63] = Gb[(size_t)mt * 64 * kCK + f];
    }
#pragma unroll
    for (int r = 0; r < 32; ++r) {
      const int f = t + 256 * r;
      hs[f >> 7][f & 127] =
          Hb[(size_t)(mt * 64 + (f >> 7)) * kC + cs * 128 + (f & 127)];
    }
    __syncthreads();

    float s[4][4];
#pragma unroll
    for (int i = 0; i < 4; ++i)
#pragma unroll
      for (int j = 0; j < 4; ++j) s[i][j] = 0.f;

#pragma unroll
    for (int k4 = 0; k4 < 64; k4 += 4) {
      float4 fv[4], gv[4];
#pragma unroll
      for (int i = 0; i < 4; ++i) fv[i] = *(const float4*)&fs[tq * 4 + i][k4];
#pragma unroll
      for (int j = 0; j < 4; ++j) gv[j] = *(const float4*)&gps[tc * 4 + j][k4];
#pragma unroll
      for (int i = 0; i < 4; ++i)
#pragma unroll
        for (int j = 0; j < 4; ++j) {
          s[i][j] += fv[i].x * gv[j].x + fv[i].y * gv[j].y +
                     fv[i].z * gv[j].z + fv[i].w * gv[j].w;
        }
    }
    __syncthreads();

    // overwrite G tile with normalized P tile
#pragma unroll
    for (int i = 0; i < 4; ++i)
#pragma unroll
      for (int j = 0; j < 4; ++j)
        gps[tq * 4 + i][tc * 4 + j] = __expf(s[i][j] - rmax[i]) * rsinv[i];
    __syncthreads();

#pragma unroll 4
    for (int m = 0; m < 64; ++m) {
      float pvv[4];
#pragma unroll
      for (int i = 0; i < 4; ++i) pvv[i] = gps[tq * 4 + i][m];
      const float4 h0 = *(const float4*)&hs[m][tc * 8];
      const float4 h1 = *(const float4*)&hs[m][tc * 8 + 4];
#pragma unroll
      for (int i = 0; i < 4; ++i) {
        acc[i][0] += pvv[i] * h0.x; acc[i][1] += pvv[i] * h0.y;
        acc[i][2] += pvv[i] * h0.z; acc[i][3] += pvv[i] * h0.w;
        acc[i][4] += pvv[i] * h1.x; acc[i][5] += pvv[i] * h1.y;
        acc[i][6] += pvv[i] * h1.z; acc[i][7] += pvv[i] * h1.w;
      }
    }
    __syncthreads();
  }

  // stage O tile through LDS for coalesced [c][n] writes
#pragma unroll
  for (int i = 0; i < 4; ++i)
#pragma unroll
    for (int u = 0; u < 8; ++u)
      hs[tq * 4 + i][tc * 8 + u] = acc[i][u];
  __syncthreads();

  const float g0 = gamma[0];
#pragma unroll
  for (int r = 0; r < 32; ++r) {
    const int f = t + 256 * r;
    const int ccol = f >> 6;   // 0..127
    const int n = f & 63;
    const size_t oidx = ((size_t)b * kC + cs * 128 + ccol) * kN + (size_t)qt * 64 + n;
    out[oidx] = g0 * hs[n][ccol] + x[oidx];
  }
}

extern "C" void kernel_launch(void* const* d_in, const int* in_sizes, int n_in,
                              void* d_out, int out_size, void* d_ws, size_t ws_size,
                              hipStream_t stream)
{
  const float* x     = (const float*)d_in[0];
  const float* Wf_w  = (const float*)d_in[1];
  const float* Wf_b  = (const float*)d_in[2];
  const float* Wg_w  = (const float*)d_in[3];
  const float* Wg_b  = (const float*)d_in[4];
  const float* Wh_w  = (const float*)d_in[5];
  const float* Wh_b  = (const float*)d_in[6];
  const float* gamma = (const float*)d_in[7];
  float* out = (float*)d_out;

  const size_t nF = (size_t)kB * kN * kCK;  // 2,097,152
  const size_t nH = (size_t)kB * kN * kC;   // 16,777,216
  const size_t nR = (size_t)kB * kN;        // 32,768

  float* F    = (float*)d_ws;
  float* G    = F + nF;
  float* Hh   = G + nF;
  float* rmax = Hh + nH;
  float* rsum = rmax + nR;
  const size_t need = (2 * nF + nH + 2 * nR) * sizeof(float);
  if (ws_size < need) return;  // insufficient scratch; fail loudly via mismatch

  dim3 blk(256);
  proj_kernel<<<dim3(kN / 64, kCK / 64, kB), blk, 0, stream>>>(x, Wf_w, Wf_b, F, kCK);
  proj_kernel<<<dim3(kN / 64, kCK / 64, kB), blk, 0, stream>>>(x, Wg_w, Wg_b, G, kCK);
  proj_kernel<<<dim3(kN / 64, kC / 64, kB), blk, 0, stream>>>(x, Wh_w, Wh_b, Hh, kC);
  stats_kernel<<<dim3(kN / 64, kB), blk, 0, stream>>>(F, G, rmax, rsum);
  pv_kernel<<<dim3(kN / 64, kC / 128, kB), blk, 0, stream>>>(x, F, G, Hh, rmax, rsum, gamma, out);
}

// Round 2
// 744.265 us; speedup vs baseline: 5.4454x; 5.4454x over previous
//
#include <hip/hip_runtime.h>

typedef __attribute__((ext_vector_type(8))) short bf16x8;
typedef __attribute__((ext_vector_type(4))) float f32x4;
typedef unsigned short u16;
typedef unsigned int u32;

namespace {
constexpr int kB = 8;
constexpr int kC = 512;
constexpr int kCK = 64;
constexpr int kN = 4096;

__device__ __forceinline__ u16 f2bf(float f) {
  union { float f; u32 u; } v; v.f = f;
  u32 r = v.u + 0x7fffu + ((v.u >> 16) & 1u);   // round-to-nearest-even
  return (u16)(r >> 16);
}
__device__ __forceinline__ f32x4 zero4() { f32x4 z = {0.f, 0.f, 0.f, 0.f}; return z; }
}

// Out = x^T @ W^T + b, emitted as bf16. transpose=0: [B][N][Kout]; =1: [B][Kout][N].
// grid: (N/64, Kout/64, B), block 256. fp32 compute.
__global__ __launch_bounds__(256)
void proj_kernel(const float* __restrict__ x, const float* __restrict__ W,
                 const float* __restrict__ bias, u16* __restrict__ out,
                 int Kout, int transpose)
{
  const int t = threadIdx.x;
  const int nt = blockIdx.x, kt = blockIdx.y, b = blockIdx.z;
  const float* xb = x + (size_t)b * kC * kN + nt * 64;

  __shared__ float xs[16][64];
  __shared__ float wst[16][65];
  __shared__ __align__(16) u16 ostage[64][72];

  const int tn = t & 15, tk = t >> 4;

  float acc[4][4];
#pragma unroll
  for (int i = 0; i < 4; ++i)
#pragma unroll
    for (int j = 0; j < 4; ++j) acc[i][j] = 0.f;

  for (int c0 = 0; c0 < kC; c0 += 16) {
#pragma unroll
    for (int r = 0; r < 4; ++r) {
      const int f = t + 256 * r;
      xs[f >> 6][f & 63] = xb[(size_t)(c0 + (f >> 6)) * kN + (f & 63)];
    }
#pragma unroll
    for (int r = 0; r < 4; ++r) {
      const int f = t + 256 * r;
      wst[f & 15][f >> 4] = W[(size_t)(kt * 64 + (f >> 4)) * kC + (c0 + (f & 15))];
    }
    __syncthreads();
#pragma unroll
    for (int cc = 0; cc < 16; ++cc) {
      float xv[4], wv[4];
#pragma unroll
      for (int i = 0; i < 4; ++i) xv[i] = xs[cc][tn * 4 + i];
#pragma unroll
      for (int j = 0; j < 4; ++j) wv[j] = wst[cc][tk * 4 + j];
#pragma unroll
      for (int i = 0; i < 4; ++i)
#pragma unroll
        for (int j = 0; j < 4; ++j) acc[i][j] += xv[i] * wv[j];
    }
    __syncthreads();
  }

  if (!transpose) {
    u16* ob = out + ((size_t)b * kN + (size_t)nt * 64) * Kout + kt * 64;
#pragma unroll
    for (int j = 0; j < 4; ++j) {
      const float bv = bias[kt * 64 + tk * 4 + j];
#pragma unroll
      for (int i = 0; i < 4; ++i)
        ob[(size_t)(tn * 4 + i) * Kout + tk * 4 + j] = f2bf(acc[i][j] + bv);
    }
  } else {
#pragma unroll
    for (int j = 0; j < 4; ++j) {
      const float bv = bias[kt * 64 + tk * 4 + j];
#pragma unroll
      for (int i = 0; i < 4; ++i)
        ostage[tk * 4 + j][tn * 4 + i] = f2bf(acc[i][j] + bv);
    }
    __syncthreads();
    u16* ob = out + ((size_t)b * Kout + kt * 64) * kN + (size_t)nt * 64;
#pragma unroll
    for (int i2 = 0; i2 < 2; ++i2) {
      const int idx = t + 256 * i2;
      const int row = idx >> 3, col8 = idx & 7;
      *(uint4*)&ob[(size_t)row * kN + col8 * 8] = *(const uint4*)&ostage[row][col8 * 8];
    }
  }
}

// Row max and 1/sum(exp) of scores S = F G^T, via MFMA on S^T = G F^T.
// grid: (N/64, B), block 256 (4 waves; wave w owns m-strip 16w..16w+16 of each tile).
__global__ __launch_bounds__(256)
void stats_kernel(const u16* __restrict__ F, const u16* __restrict__ G,
                  float* __restrict__ rowmax, float* __restrict__ rsinv)
{
  const int t = threadIdx.x;
  const int qt = blockIdx.x, b = blockIdx.y;
  const int wave = t >> 6, lane = t & 63, lq = lane & 15, lk = lane >> 4;

  const u16* Fb = F + (size_t)b * kN * kCK;
  const u16* Gb = G + (size_t)b * kN * kCK;

  // F fragments (B operand: col=q, k contiguous) hoisted for the whole kernel
  bf16x8 fF[4][2];
#pragma unroll
  for (int ct = 0; ct < 4; ++ct)
#pragma unroll
    for (int ks = 0; ks < 2; ++ks)
      fF[ct][ks] = *(const bf16x8*)&Fb[(size_t)(qt * 64 + ct * 16 + lq) * kCK + lk * 8 + ks * 32];

  float mold[4], lsum[4];
#pragma unroll
  for (int ct = 0; ct < 4; ++ct) { mold[ct] = -3.0e38f; lsum[ct] = 0.f; }

  // prefetch G fragments (A operand: row=m, k contiguous) for mt=0
  bf16x8 g0c = *(const bf16x8*)&Gb[(size_t)(wave * 16 + lq) * kCK + lk * 8];
  bf16x8 g1c = *(const bf16x8*)&Gb[(size_t)(wave * 16 + lq) * kCK + lk * 8 + 32];

  for (int mt = 0; mt < kN / 64; ++mt) {
    const int mtn = (mt + 1 < kN / 64) ? mt + 1 : mt;
    const size_t gbase = (size_t)(mtn * 64 + wave * 16 + lq) * kCK + lk * 8;
    bf16x8 g0n = *(const bf16x8*)&Gb[gbase];
    bf16x8 g1n = *(const bf16x8*)&Gb[gbase + 32];

    f32x4 s[4];
#pragma unroll
    for (int ct = 0; ct < 4; ++ct) {
      s[ct] = zero4();
      s[ct] = __builtin_amdgcn_mfma_f32_16x16x32_bf16(g0c, fF[ct][0], s[ct], 0, 0, 0);
      s[ct] = __builtin_amdgcn_mfma_f32_16x16x32_bf16(g1c, fF[ct][1], s[ct], 0, 0, 0);
    }
#pragma unroll
    for (int ct = 0; ct < 4; ++ct) {
      float tm = fmaxf(fmaxf(s[ct][0], s[ct][1]), fmaxf(s[ct][2], s[ct][3]));
      tm = fmaxf(tm, __shfl_xor(tm, 16));
      tm = fmaxf(tm, __shfl_xor(tm, 32));
      const float mnew = fmaxf(mold[ct], tm);
      float ls = __expf(s[ct][0] - mnew) + __expf(s[ct][1] - mnew) +
                 __expf(s[ct][2] - mnew) + __expf(s[ct][3] - mnew);
      ls += __shfl_xor(ls, 16);
      ls += __shfl_xor(ls, 32);
      lsum[ct] = lsum[ct] * __expf(mold[ct] - mnew) + ls;
      mold[ct] = mnew;
    }
    g0c = g0n; g1c = g1n;
  }

  __shared__ float red[2][4][64];
  if (lane < 16) {
#pragma unroll
    for (int ct = 0; ct < 4; ++ct) {
      red[0][wave][ct * 16 + lane] = mold[ct];
      red[1][wave][ct * 16 + lane] = lsum[ct];
    }
  }
  __syncthreads();
  if (t < 64) {
    float M = fmaxf(fmaxf(red[0][0][t], red[0][1][t]), fmaxf(red[0][2][t], red[0][3][t]));
    float L = 0.f;
#pragma unroll
    for (int w = 0; w < 4; ++w) L += red[1][w][t] * __expf(red[0][w][t] - M);
    rowmax[(size_t)b * kN + qt * 64 + t] = M;
    rsinv[(size_t)b * kN + qt * 64 + t] = 1.f / L;
  }
}

// O^T[c][q] = sum_m H^T[c][m] P^T[m][q]; P = exp(S - M) * rsinv (pre-normalized).
// out = gamma * O + x. grid: (N/64, C/128, B), block 256.
// Wave w: S^T m-strip [16w,16w+16); PV c-strip [32w,32w+32). Only P goes via LDS.
__global__ __launch_bounds__(256)
void pv_kernel(const float* __restrict__ x, const u16* __restrict__ F,
               const u16* __restrict__ G, const u16* __restrict__ HT,
               const float* __restrict__ rowmax, const float* __restrict__ rsinv,
               const float* __restrict__ gamma, float* __restrict__ out)
{
  const int t = threadIdx.x;
  const int qt = blockIdx.x, cs = blockIdx.y, b = blockIdx.z;
  const int wave = t >> 6, lane = t & 63, lq = lane & 15, lk = lane >> 4;

  const u16* Fb = F + (size_t)b * kN * kCK;
  const u16* Gb = G + (size_t)b * kN * kCK;
  const u16* Hb = HT + (size_t)b * kC * kN;

  __shared__ __align__(16) char smem[64 * 132 * 4];
  u16 (*Ps)[72] = (u16(*)[72])smem;   // P^T tile: [q][m], padded rows

  float rmax[4], rsv[4];
#pragma unroll
  for (int ct = 0; ct < 4; ++ct) {
    const size_t q = (size_t)b * kN + qt * 64 + ct * 16 + lq;
    rmax[ct] = rowmax[q];
    rsv[ct] = rsinv[q];
  }
  const float g0 = gamma[0];

  bf16x8 fF[4][2];
#pragma unroll
  for (int ct = 0; ct < 4; ++ct)
#pragma unroll
    for (int ks = 0; ks < 2; ++ks)
      fF[ct][ks] = *(const bf16x8*)&Fb[(size_t)(qt * 64 + ct * 16 + lq) * kCK + lk * 8 + ks * 32];

  f32x4 acc[2][4];
#pragma unroll
  for (int ci = 0; ci < 2; ++ci)
#pragma unroll
    for (int ct = 0; ct < 4; ++ct) acc[ci][ct] = zero4();

  // G fragment prefetch for mt=0
  bf16x8 gc[2];
  {
    const size_t gbase = (size_t)(wave * 16 + lq) * kCK + lk * 8;
    gc[0] = *(const bf16x8*)&Gb[gbase];
    gc[1] = *(const bf16x8*)&Gb[gbase + 32];
  }

  for (int mt = 0; mt < kN / 64; ++mt) {
    // issue H^T fragment loads for THIS mt first: consumed only after the barrier,
    // so ~whole S+exp phase covers their latency (barriers below don't drain vmcnt).
    bf16x8 hc[2][2];
#pragma unroll
    for (int ci = 0; ci < 2; ++ci) {
      const size_t hbase =
          (size_t)(cs * 128 + wave * 32 + ci * 16 + lq) * kN + (size_t)mt * 64 + lk * 8;
      hc[ci][0] = *(const bf16x8*)&Hb[hbase];
      hc[ci][1] = *(const bf16x8*)&Hb[hbase + 32];
    }

    // S^T tile: D[m][q], m-strip of this wave
    f32x4 s[4];
#pragma unroll
    for (int ct = 0; ct < 4; ++ct) {
      s[ct] = zero4();
      s[ct] = __builtin_amdgcn_mfma_f32_16x16x32_bf16(gc[0], fF[ct][0], s[ct], 0, 0, 0);
      s[ct] = __builtin_amdgcn_mfma_f32_16x16x32_bf16(gc[1], fF[ct][1], s[ct], 0, 0, 0);
    }

    // prefetch G for mt+1 (covered by barrier + PV phase)
    {
      const int mtn = (mt + 1 < kN / 64) ? mt + 1 : mt;
      const size_t gbase = (size_t)(mtn * 64 + wave * 16 + lq) * kCK + lk * 8;
      gc[0] = *(const bf16x8*)&Gb[gbase];
      gc[1] = *(const bf16x8*)&Gb[gbase + 32];
    }

    // normalized P -> bf16 -> LDS. D row (lane>>4)*4+r = 4 consecutive m: one b64 write.
#pragma unroll
    for (int ct = 0; ct < 4; ++ct) {
      const float p0 = __expf(s[ct][0] - rmax[ct]) * rsv[ct];
      const float p1 = __expf(s[ct][1] - rmax[ct]) * rsv[ct];
      const float p2 = __expf(s[ct][2] - rmax[ct]) * rsv[ct];
      const float p3 = __expf(s[ct][3] - rmax[ct]) * rsv[ct];
      uint2 pk;
      pk.x = (u32)f2bf(p0) | ((u32)f2bf(p1) << 16);
      pk.y = (u32)f2bf(p2) | ((u32)f2bf(p3) << 16);
      *(uint2*)&Ps[ct * 16 + lq][wave * 16 + lk * 4] = pk;
    }

    // barrier WITHOUT vmcnt drain: P visible to all waves, global loads stay in flight
    asm volatile("s_waitcnt lgkmcnt(0)\n\ts_barrier" ::: "memory");

    // PV: acc[ci][ct] += H^T-frag x P-frag
    bf16x8 pB[4][2];
#pragma unroll
    for (int ct = 0; ct < 4; ++ct) {
      pB[ct][0] = *(const bf16x8*)&Ps[ct * 16 + lq][lk * 8];
      pB[ct][1] = *(const bf16x8*)&Ps[ct * 16 + lq][lk * 8 + 32];
    }
#pragma unroll
    for (int ci = 0; ci < 2; ++ci)
#pragma unroll
      for (int ct = 0; ct < 4; ++ct) {
        acc[ci][ct] = __builtin_amdgcn_mfma_f32_16x16x32_bf16(hc[ci][0], pB[ct][0], acc[ci][ct], 0, 0, 0);
        acc[ci][ct] = __builtin_amdgcn_mfma_f32_16x16x32_bf16(hc[ci][1], pB[ct][1], acc[ci][ct], 0, 0, 0);
      }

    // protect Ps reuse next iteration (again no vmcnt drain)
    asm volatile("s_waitcnt lgkmcnt(0)\n\ts_barrier" ::: "memory");
  }

  // epilogue: stage O^T through LDS (reuses smem; safe after final barrier)
  float (*Os)[132] = (float(*)[132])smem;
#pragma unroll
  for (int ci = 0; ci < 2; ++ci)
#pragma unroll
    for (int ct = 0; ct < 4; ++ct)
#pragma unroll
      for (int r = 0; r < 4; ++r)
        Os[ct * 16 + lq][wave * 32 + ci * 16 + lk * 4 + r] = acc[ci][ct][r];
  __syncthreads();

  const size_t obase = ((size_t)b * kC + (size_t)cs * 128) * kN + (size_t)qt * 64;
#pragma unroll
  for (int i = 0; i < 32; ++i) {
    const int f = t + 256 * i;
    const int c = f >> 6, n = f & 63;
    const size_t idx = obase + (size_t)c * kN + n;
    out[idx] = g0 * Os[n][c] + x[idx];
  }
}

extern "C" void kernel_launch(void* const* d_in, const int* in_sizes, int n_in,
                              void* d_out, int out_size, void* d_ws, size_t ws_size,
                              hipStream_t stream)
{
  const float* x     = (const float*)d_in[0];
  const float* Wf_w  = (const float*)d_in[1];
  const float* Wf_b  = (const float*)d_in[2];
  const float* Wg_w  = (const float*)d_in[3];
  const float* Wg_b  = (const float*)d_in[4];
  const float* Wh_w  = (const float*)d_in[5];
  const float* Wh_b  = (const float*)d_in[6];
  const float* gamma = (const float*)d_in[7];
  float* out = (float*)d_out;

  const size_t nF = (size_t)kB * kN * kCK;   // 2,097,152
  const size_t nH = (size_t)kB * kC * kN;    // 16,777,216
  const size_t nR = (size_t)kB * kN;         // 32,768

  u16* F  = (u16*)d_ws;
  u16* G  = F + nF;
  u16* HT = G + nF;
  float* rowmax = (float*)(HT + nH);
  float* rsinv  = rowmax + nR;
  const size_t need = (2 * nF + nH) * sizeof(u16) + 2 * nR * sizeof(float);
  if (ws_size < need) return;

  dim3 blk(256);
  proj_kernel<<<dim3(kN / 64, 1, kB), blk, 0, stream>>>(x, Wf_w, Wf_b, F, kCK, 0);
  proj_kernel<<<dim3(kN / 64, 1, kB), blk, 0, stream>>>(x, Wg_w, Wg_b, G, kCK, 0);
  proj_kernel<<<dim3(kN / 64, kC / 64, kB), blk, 0, stream>>>(x, Wh_w, Wh_b, HT, kC, 1);
  stats_kernel<<<dim3(kN / 64, kB), blk, 0, stream>>>(F, G, rowmax, rsinv);
  pv_kernel<<<dim3(kN / 64, kC / 128, kB), blk, 0, stream>>>(x, F, G, HT, rowmax, rsinv, gamma, out);
}

// Round 3
// 409.979 us; speedup vs baseline: 9.8855x; 1.8154x over previous
//
#include <hip/hip_runtime.h>

typedef __attribute__((ext_vector_type(8))) short bf16x8;
typedef __attribute__((ext_vector_type(4))) float f32x4;
typedef __attribute__((ext_vector_type(16))) float f32x16;
typedef unsigned short u16;
typedef unsigned int u32;

namespace {
constexpr int kB = 8;
constexpr int kC = 512;
constexpr int kCK = 64;
constexpr int kN = 4096;

__device__ __forceinline__ u16 f2bf(float f) {
  union { float f; u32 u; } v; v.f = f;
  u32 r = v.u + 0x7fffu + ((v.u >> 16) & 1u);   // RNE
  return (u16)(r >> 16);
}
__device__ __forceinline__ u32 pk2bf(float a, float b) {
  return (u32)f2bf(a) | ((u32)f2bf(b) << 16);
}
__device__ __forceinline__ f32x4 zero4() { f32x4 z = {0.f, 0.f, 0.f, 0.f}; return z; }
}

// Cast Wf(64x512), Wg(64x512), Wh(512x512) fp32 -> bf16 into Wcat[640][512].
__global__ __launch_bounds__(256)
void wcast_kernel(const float* __restrict__ Wf, const float* __restrict__ Wg,
                  const float* __restrict__ Wh, u16* __restrict__ Wcat)
{
  const int idx = blockIdx.x * 256 + threadIdx.x;   // one float4 each
  const int e = idx * 4;                            // 0 .. 327680
  const int row = e >> 9, col = e & 511;
  const float* src = (row < 64) ? &Wf[(size_t)row * 512 + col]
                   : (row < 128) ? &Wg[(size_t)(row - 64) * 512 + col]
                                 : &Wh[(size_t)(row - 128) * 512 + col];
  const float4 v = *(const float4*)src;
  uint2 pk;
  pk.x = pk2bf(v.x, v.y);
  pk.y = pk2bf(v.z, v.w);
  *(uint2*)&Wcat[e] = pk;
}

// Fused projections via MFMA. Per block: one 64-column slab of x (all C),
// staged transposed in LDS as bf16; computes F[n][64], G[n][64], HT[C][n].
// grid: (N/64, B), block 256 (4 waves).
__global__ __launch_bounds__(256, 2)
void fused_proj_kernel(const float* __restrict__ x, const u16* __restrict__ Wcat,
                       const float* __restrict__ Wf_b, const float* __restrict__ Wg_b,
                       const float* __restrict__ Wh_b,
                       u16* __restrict__ F, u16* __restrict__ G, u16* __restrict__ HT)
{
  const int t = threadIdx.x;
  const int nt = blockIdx.x, b = blockIdx.y;
  const int wave = t >> 6, lane = t & 63, lq = lane & 15, lk = lane >> 4;

  __shared__ __align__(16) u16 xt[64][536];   // [n][c], row stride 1072B

  // ---- stage x^T tile (cast to bf16). Coalesced row reads, packed b64 writes.
  const float* xb = x + (size_t)b * kC * kN + (size_t)nt * 64;
  for (int c0 = 0; c0 < kC; c0 += 16) {
    const int c = c0 + wave * 4;
    const size_t base = (size_t)c * kN + lane;
    const float v0 = xb[base];
    const float v1 = xb[base + kN];
    const float v2 = xb[base + 2 * (size_t)kN];
    const float v3 = xb[base + 3 * (size_t)kN];
    uint2 pk; pk.x = pk2bf(v0, v1); pk.y = pk2bf(v2, v3);
    *(uint2*)&xt[lane][c] = pk;
  }
  __syncthreads();

  // ---- MFMA: ks-outer, all 10 output k-tiles accumulated simultaneously.
  // F/G: D[k][n] (A = W-row, B = xt).  H: D[n][cout] (A = xt, B = Wh-row).
  f32x4 accF[4], accG[4], accH[8][4];
#pragma unroll
  for (int ni = 0; ni < 4; ++ni) { accF[ni] = zero4(); accG[ni] = zero4(); }
#pragma unroll
  for (int cj = 0; cj < 8; ++cj)
#pragma unroll
    for (int ni = 0; ni < 4; ++ni) accH[cj][ni] = zero4();

  for (int ks = 0; ks < 16; ++ks) {
    const int kb = ks * 32 + lk * 8;
    bf16x8 xf[4];
#pragma unroll
    for (int ni = 0; ni < 4; ++ni)
      xf[ni] = *(const bf16x8*)&xt[ni * 16 + lq][kb];

    const bf16x8 wf = *(const bf16x8*)&Wcat[(size_t)(wave * 16 + lq) * 512 + kb];
    const bf16x8 wg = *(const bf16x8*)&Wcat[(size_t)(64 + wave * 16 + lq) * 512 + kb];
    bf16x8 wh[8];
#pragma unroll
    for (int cj = 0; cj < 8; ++cj)
      wh[cj] = *(const bf16x8*)&Wcat[(size_t)(128 + wave * 128 + cj * 16 + lq) * 512 + kb];

#pragma unroll
    for (int ni = 0; ni < 4; ++ni) {
      accF[ni] = __builtin_amdgcn_mfma_f32_16x16x32_bf16(wf, xf[ni], accF[ni], 0, 0, 0);
      accG[ni] = __builtin_amdgcn_mfma_f32_16x16x32_bf16(wg, xf[ni], accG[ni], 0, 0, 0);
#pragma unroll
      for (int cj = 0; cj < 8; ++cj)
        accH[cj][ni] = __builtin_amdgcn_mfma_f32_16x16x32_bf16(xf[ni], wh[cj], accH[cj][ni], 0, 0, 0);
    }
  }

  // ---- epilogue
  u16* Fb = F + (size_t)b * kN * kCK;
  u16* Gb = G + (size_t)b * kN * kCK;
  u16* Hb = HT + (size_t)b * kC * kN;

  {
    const float4 bf = *(const float4*)&Wf_b[wave * 16 + lk * 4];
    const float4 bg = *(const float4*)&Wg_b[wave * 16 + lk * 4];
#pragma unroll
    for (int ni = 0; ni < 4; ++ni) {
      const size_t nrow = (size_t)(nt * 64 + ni * 16 + lq);
      uint2 pf, pg;
      pf.x = pk2bf(accF[ni][0] + bf.x, accF[ni][1] + bf.y);
      pf.y = pk2bf(accF[ni][2] + bf.z, accF[ni][3] + bf.w);
      pg.x = pk2bf(accG[ni][0] + bg.x, accG[ni][1] + bg.y);
      pg.y = pk2bf(accG[ni][2] + bg.z, accG[ni][3] + bg.w);
      *(uint2*)&Fb[nrow * kCK + wave * 16 + lk * 4] = pf;
      *(uint2*)&Gb[nrow * kCK + wave * 16 + lk * 4] = pg;
    }
  }
#pragma unroll
  for (int cj = 0; cj < 8; ++cj) {
    const int cout = wave * 128 + cj * 16 + lq;
    const float bh = Wh_b[cout];
#pragma unroll
    for (int ni = 0; ni < 4; ++ni) {
      uint2 ph;
      ph.x = pk2bf(accH[cj][ni][0] + bh, accH[cj][ni][1] + bh);
      ph.y = pk2bf(accH[cj][ni][2] + bh, accH[cj][ni][3] + bh);
      *(uint2*)&Hb[(size_t)cout * kN + nt * 64 + ni * 16 + lk * 4] = ph;
    }
  }
}

// Row max and 1/sum(exp) of scores S = F G^T, via MFMA on S^T = G F^T.
// grid: 512 (b = bid&7 for XCD/L2 locality), block 256.
__global__ __launch_bounds__(256)
void stats_kernel(const u16* __restrict__ F, const u16* __restrict__ G,
                  float* __restrict__ rowmax, float* __restrict__ rsinv)
{
  const int t = threadIdx.x;
  const int bid = blockIdx.x;
  const int b = bid & 7, qt = bid >> 3;
  const int wave = t >> 6, lane = t & 63, lq = lane & 15, lk = lane >> 4;

  const u16* Fb = F + (size_t)b * kN * kCK;
  const u16* Gb = G + (size_t)b * kN * kCK;

  bf16x8 fF[4][2];
#pragma unroll
  for (int ct = 0; ct < 4; ++ct)
#pragma unroll
    for (int ks = 0; ks < 2; ++ks)
      fF[ct][ks] = *(const bf16x8*)&Fb[(size_t)(qt * 64 + ct * 16 + lq) * kCK + lk * 8 + ks * 32];

  float mold[4], lsum[4];
#pragma unroll
  for (int ct = 0; ct < 4; ++ct) { mold[ct] = -3.0e38f; lsum[ct] = 0.f; }

  bf16x8 g0c = *(const bf16x8*)&Gb[(size_t)(wave * 16 + lq) * kCK + lk * 8];
  bf16x8 g1c = *(const bf16x8*)&Gb[(size_t)(wave * 16 + lq) * kCK + lk * 8 + 32];

  for (int mt = 0; mt < kN / 64; ++mt) {
    const int mtn = (mt + 1 < kN / 64) ? mt + 1 : mt;
    const size_t gbase = (size_t)(mtn * 64 + wave * 16 + lq) * kCK + lk * 8;
    bf16x8 g0n = *(const bf16x8*)&Gb[gbase];
    bf16x8 g1n = *(const bf16x8*)&Gb[gbase + 32];

    f32x4 s[4];
#pragma unroll
    for (int ct = 0; ct < 4; ++ct) {
      s[ct] = zero4();
      s[ct] = __builtin_amdgcn_mfma_f32_16x16x32_bf16(g0c, fF[ct][0], s[ct], 0, 0, 0);
      s[ct] = __builtin_amdgcn_mfma_f32_16x16x32_bf16(g1c, fF[ct][1], s[ct], 0, 0, 0);
    }
#pragma unroll
    for (int ct = 0; ct < 4; ++ct) {
      float tm = fmaxf(fmaxf(s[ct][0], s[ct][1]), fmaxf(s[ct][2], s[ct][3]));
      tm = fmaxf(tm, __shfl_xor(tm, 16));
      tm = fmaxf(tm, __shfl_xor(tm, 32));
      const float mnew = fmaxf(mold[ct], tm);
      float ls = __expf(s[ct][0] - mnew) + __expf(s[ct][1] - mnew) +
                 __expf(s[ct][2] - mnew) + __expf(s[ct][3] - mnew);
      ls += __shfl_xor(ls, 16);
      ls += __shfl_xor(ls, 32);
      lsum[ct] = lsum[ct] * __expf(mold[ct] - mnew) + ls;
      mold[ct] = mnew;
    }
    g0c = g0n; g1c = g1n;
  }

  __shared__ float red[2][4][64];
  if (lane < 16) {
#pragma unroll
    for (int ct = 0; ct < 4; ++ct) {
      red[0][wave][ct * 16 + lane] = mold[ct];
      red[1][wave][ct * 16 + lane] = lsum[ct];
    }
  }
  __syncthreads();
  if (t < 64) {
    float M = fmaxf(fmaxf(red[0][0][t], red[0][1][t]), fmaxf(red[0][2][t], red[0][3][t]));
    float L = 0.f;
#pragma unroll
    for (int w = 0; w < 4; ++w) L += red[1][w][t] * __expf(red[0][w][t] - M);
    rowmax[(size_t)b * kN + qt * 64 + t] = M;
    rsinv[(size_t)b * kN + qt * 64 + t] = 1.f / L;
  }
}

// O^T[c][q] = sum_m H^T[c][m] P^T[m][q]; P pre-normalized. out = gamma*O + x.
// grid: 1024 1-D (b = bid&7 -> XCD pinning; qt = (bid>>3)&63; cs = bid>>9).
// Per block: 64 q x 256 c. Wave w: S m-strip [16w,16w+16); PV c-strip [64w,64w+64).
// PV uses 32x32x16 MFMA; Ps double-buffered -> one barrier per mt.
__global__ __launch_bounds__(256, 2)
void pv_kernel(const float* __restrict__ x, const u16* __restrict__ F,
               const u16* __restrict__ G, const u16* __restrict__ HT,
               const float* __restrict__ rowmax, const float* __restrict__ rsinv,
               const float* __restrict__ gamma, float* __restrict__ out)
{
  const int t = threadIdx.x;
  const int bid = blockIdx.x;
  const int b  = bid & 7;
  const int qt = (bid >> 3) & 63;
  const int cs = bid >> 9;
  const int wave = t >> 6, lane = t & 63, lq = lane & 15, lk = lane >> 4;
  const int l31 = lane & 31, hi = lane >> 5;

  const u16* Fb = F + (size_t)b * kN * kCK;
  const u16* Gb = G + (size_t)b * kN * kCK;
  const u16* Hb = HT + (size_t)b * kC * kN;

  __shared__ __align__(16) u16 Ps[2][64][72];   // [buf][q][m]

  float rmax[4], rsv[4];
#pragma unroll
  for (int ct = 0; ct < 4; ++ct) {
    const size_t q = (size_t)b * kN + qt * 64 + ct * 16 + lq;
    rmax[ct] = rowmax[q];
    rsv[ct] = rsinv[q];
  }
  const float g0 = gamma[0];

  bf16x8 fF[4][2];
#pragma unroll
  for (int ct = 0; ct < 4; ++ct)
#pragma unroll
    for (int ks = 0; ks < 2; ++ks)
      fF[ct][ks] = *(const bf16x8*)&Fb[(size_t)(qt * 64 + ct * 16 + lq) * kCK + lk * 8 + ks * 32];

  f32x16 acc[2][2];
#pragma unroll
  for (int ci = 0; ci < 2; ++ci)
#pragma unroll
    for (int cq = 0; cq < 2; ++cq)
#pragma unroll
      for (int r = 0; r < 16; ++r) acc[ci][cq][r] = 0.f;

  bf16x8 gc[2];
  {
    const size_t gbase = (size_t)(wave * 16 + lq) * kCK + lk * 8;
    gc[0] = *(const bf16x8*)&Gb[gbase];
    gc[1] = *(const bf16x8*)&Gb[gbase + 32];
  }

  for (int mt = 0; mt < kN / 64; ++mt) {
    const int buf = mt & 1;

    // H^T A-frags for this mt (consumed after the barrier; latency hidden by S phase)
    bf16x8 hc[2][4];
#pragma unroll
    for (int ci = 0; ci < 2; ++ci) {
      const size_t hrow = (size_t)(cs * 256 + wave * 64 + ci * 32 + l31) * kN + (size_t)mt * 64;
#pragma unroll
      for (int ks = 0; ks < 4; ++ks)
        hc[ci][ks] = *(const bf16x8*)&Hb[hrow + ks * 16 + hi * 8];
    }

    // S^T m-strip via 16x16x32
    f32x4 s[4];
#pragma unroll
    for (int ct = 0; ct < 4; ++ct) {
      s[ct] = zero4();
      s[ct] = __builtin_amdgcn_mfma_f32_16x16x32_bf16(gc[0], fF[ct][0], s[ct], 0, 0, 0);
      s[ct] = __builtin_amdgcn_mfma_f32_16x16x32_bf16(gc[1], fF[ct][1], s[ct], 0, 0, 0);
    }

    // G prefetch for mt+1
    {
      const int mtn = (mt + 1 < kN / 64) ? mt + 1 : mt;
      const size_t gbase = (size_t)(mtn * 64 + wave * 16 + lq) * kCK + lk * 8;
      gc[0] = *(const bf16x8*)&Gb[gbase];
      gc[1] = *(const bf16x8*)&Gb[gbase + 32];
    }

    // normalized P -> bf16 -> Ps[buf]
#pragma unroll
    for (int ct = 0; ct < 4; ++ct) {
      const float p0 = __expf(s[ct][0] - rmax[ct]) * rsv[ct];
      const float p1 = __expf(s[ct][1] - rmax[ct]) * rsv[ct];
      const float p2 = __expf(s[ct][2] - rmax[ct]) * rsv[ct];
      const float p3 = __expf(s[ct][3] - rmax[ct]) * rsv[ct];
      uint2 pk; pk.x = pk2bf(p0, p1); pk.y = pk2bf(p2, p3);
      *(uint2*)&Ps[buf][ct * 16 + lq][wave * 16 + lk * 4] = pk;
    }

    // single barrier per mt (double-buffered Ps); no vmcnt drain
    asm volatile("s_waitcnt lgkmcnt(0)\n\ts_barrier" ::: "memory");

    bf16x8 pB[2][4];
#pragma unroll
    for (int cq = 0; cq < 2; ++cq)
#pragma unroll
      for (int ks = 0; ks < 4; ++ks)
        pB[cq][ks] = *(const bf16x8*)&Ps[buf][cq * 32 + l31][ks * 16 + hi * 8];

#pragma unroll
    for (int ks = 0; ks < 4; ++ks)
#pragma unroll
      for (int ci = 0; ci < 2; ++ci)
#pragma unroll
        for (int cq = 0; cq < 2; ++cq)
          acc[ci][cq] = __builtin_amdgcn_mfma_f32_32x32x16_bf16(hc[ci][ks], pB[cq][ks], acc[ci][cq], 0, 0, 0);
  }

  // epilogue: D col = lane&31 = q, row = (reg&3) + 8*(reg>>2) + 4*hi = c-within-32
#pragma unroll
  for (int ci = 0; ci < 2; ++ci)
#pragma unroll
    for (int cq = 0; cq < 2; ++cq)
#pragma unroll
      for (int r = 0; r < 16; ++r) {
        const int crow = (r & 3) + 8 * (r >> 2) + 4 * hi;
        const int c = cs * 256 + wave * 64 + ci * 32 + crow;
        const int n = qt * 64 + cq * 32 + l31;
        const size_t idx = ((size_t)b * kC + c) * kN + n;
        out[idx] = g0 * acc[ci][cq][r] + x[idx];
      }
}

extern "C" void kernel_launch(void* const* d_in, const int* in_sizes, int n_in,
                              void* d_out, int out_size, void* d_ws, size_t ws_size,
                              hipStream_t stream)
{
  const float* x     = (const float*)d_in[0];
  const float* Wf_w  = (const float*)d_in[1];
  const float* Wf_b  = (const float*)d_in[2];
  const float* Wg_w  = (const float*)d_in[3];
  const float* Wg_b  = (const float*)d_in[4];
  const float* Wh_w  = (const float*)d_in[5];
  const float* Wh_b  = (const float*)d_in[6];
  const float* gamma = (const float*)d_in[7];
  float* out = (float*)d_out;

  const size_t nF = (size_t)kB * kN * kCK;   // 2,097,152
  const size_t nH = (size_t)kB * kC * kN;    // 16,777,216
  const size_t nR = (size_t)kB * kN;         // 32,768
  const size_t nW = 640 * 512;               // 327,680

  u16* F  = (u16*)d_ws;
  u16* G  = F + nF;
  u16* HT = G + nF;
  u16* Wcat = HT + nH;
  float* rowmax = (float*)(Wcat + nW);
  float* rsinv  = rowmax + nR;
  const size_t need = (2 * nF + nH + nW) * sizeof(u16) + 2 * nR * sizeof(float);
  if (ws_size < need) return;

  dim3 blk(256);
  wcast_kernel<<<dim3(nW / 1024), blk, 0, stream>>>(Wf_w, Wg_w, Wh_w, Wcat);
  fused_proj_kernel<<<dim3(kN / 64, kB), blk, 0, stream>>>(x, Wcat, Wf_b, Wg_b, Wh_b, F, G, HT);
  stats_kernel<<<dim3(512), blk, 0, stream>>>(F, G, rowmax, rsinv);
  pv_kernel<<<dim3(1024), blk, 0, stream>>>(x, F, G, HT, rowmax, rsinv, gamma, out);
}